// Round 22
// baseline (320.322 us; speedup 1.0000x reference)
//
#include <hip/hip_runtime.h>

typedef unsigned short u16;
typedef __attribute__((ext_vector_type(8))) _Float16 f16x8;
typedef __attribute__((ext_vector_type(4))) float f32x4;

#define MFMAH(a, b, c) __builtin_amdgcn_mfma_f32_16x16x32_f16((a), (b), (c), 0, 0, 0)

__device__ __forceinline__ u16 f2h(float f) {
  _Float16 h = (_Float16)f;  // v_cvt_f16_f32, RNE
  return __builtin_bit_cast(u16, h);
}
__device__ __forceinline__ float h2f(u16 h) {
  return (float)__builtin_bit_cast(_Float16, h);
}
__device__ __forceinline__ unsigned pk_h(float a, float b) {  // RNE pair
  return (unsigned)f2h(a) | ((unsigned)f2h(b) << 16);
}
__device__ __forceinline__ unsigned pkrtz(float a, float b) {  // 1-inst packed cvt (RTZ)
  unsigned r;
  asm("v_cvt_pkrtz_f16_f32 %0, %1, %2" : "=v"(r) : "v"(a), "v"(b));
  return r;
}

// ---------------- fused prep: cast x, w_qkv, w_fc to f16 (one launch) ----------------
__global__ void prep_cast(const float* __restrict__ x, u16* __restrict__ xh,
                          const float* __restrict__ wqf, u16* __restrict__ wq,
                          const float* __restrict__ wff, u16* __restrict__ wf,
                          long nx, long nq, long nf) {
  long total = nx + nq + nf;
  long stride = (long)gridDim.x * blockDim.x;
  for (long i = (long)blockIdx.x * blockDim.x + threadIdx.x; i < total; i += stride) {
    const float4* src;
    ushort4* dst;
    long j;
    if (i < nx) { src = (const float4*)x; dst = (ushort4*)xh; j = i; }
    else if (i < nx + nq) { src = (const float4*)wqf; dst = (ushort4*)wq; j = i - nx; }
    else { src = (const float4*)wff; dst = (ushort4*)wf; j = i - nx - nq; }
    float4 v = src[j];
    ushort4 h;
    h.x = f2h(v.x); h.y = f2h(v.y); h.z = f2h(v.z); h.w = f2h(v.w);
    dst[j] = h;
  }
}

// ---------------- cos/sin table: (b, t-1, i) -> float2(c,s); 16 heads share positions ----------------
__global__ void cs_table_kernel(const int* __restrict__ pos, float2* __restrict__ cst) {
  int idx = blockIdx.x * 256 + threadIdx.x;  // exactly B*2048*32 threads
  int i = idx & 31;
  int r = idx >> 5;
  int ti = r & 2047;
  int b = r >> 11;
  int p = pos[b * 2048 + ti];
  // replicate reference fp32 rounding of freq and angle, then exact trig
  float fr = (float)pow(10000.0, -(double)i / 32.0);
  float angf = (float)p * fr;
  double sd, cd;
  sincos((double)angf, &sd, &cd);
  cst[idx] = make_float2((float)cd, (float)sd);
}

// ---------------- pads: zero K rows [N,NP) and V^T cols [N,NP) (f16) ----------------
__global__ void pad_kernel(u16* __restrict__ kh, u16* __restrict__ vth, int N, int NP) {
  const int PW = NP - N;                 // 63 pad tokens
  const int PART1 = 64 * PW * 32;        // u32 words for K pad rows
  const int PART2 = 64 * 64 * PW;        // u16 elems for V^T pad cols
  int idx = blockIdx.x * 256 + threadIdx.x;
  if (idx < PART1) {
    int per_bh = PW * 32;
    int bh = idx / per_bh, r = idx - bh * per_bh;
    size_t u = (((size_t)bh * NP + N) * 64 >> 1) + r;
    ((unsigned*)kh)[u] = 0;
  } else if (idx < PART1 + PART2) {
    int j = idx - PART1;
    int per_bh = 64 * PW;
    int bh = j / per_bh, r = j - bh * per_bh;
    int d = r / PW, t = N + (r - d * PW);
    vth[(size_t)bh * 64 * NP + (size_t)d * NP + t] = 0;
  }
}

// ================= f16 GEMM (R21 champion + L2-blocked traversal for EPI 0) =================
// BM=128 x BN=128 x BK=32, 256 thr = 4 waves, wave-tile 64x64, 2-phase dbuf, 32 KB LDS
// -> 5 blocks/CU.  R21 counter: FETCH 154 MB vs ~40 MB unique -> per-XCD working set
// (x-stripe 2.1 + full wq 6.3 MB) overflows the 4 MB L2.  Fix: 8M x 6N super-tile order
// within each XCD chunk -> working set 2.1 + 1.6 = 3.7 MB < 4 MB (x fetched once globally,
// wq once per XCD).  Pure bijective remap; arithmetic unchanged.
__device__ __forceinline__ int swz_off(int R, int lg) {
  return R * 32 + ((lg ^ ((R >> 1) & 3)) << 3);
}
__device__ __forceinline__ const u16* stage_src(const u16* __restrict__ g, int row0, int rmax,
                                                int K, int c) {
  int row = c >> 2;
  int kc = (((c & 3) ^ ((c >> 3) & 3)) << 3);
  int gr = row0 + row;
  if (gr > rmax) gr = rmax;
  return g + (size_t)gr * K + kc;
}
__device__ __forceinline__ void stage2(const u16* p0, const u16* p1, u16* l, int k0, int tid) {
  __builtin_amdgcn_global_load_lds((const __attribute__((address_space(1))) void*)(p0 + k0),
                                   (__attribute__((address_space(3))) void*)(l + tid * 8),
                                   16, 0, 0);
  __builtin_amdgcn_global_load_lds((const __attribute__((address_space(1))) void*)(p1 + k0),
                                   (__attribute__((address_space(3))) void*)(l + 2048 + tid * 8),
                                   16, 0, 0);
}

// EPI 0: fused RoPE + f16 q/k epilogue + direct-transposed v.  EPI 1: fp32 out + bias.
template <int EPI>
__global__ __launch_bounds__(256) void gemm_s1(
    const u16* __restrict__ Aw, const u16* __restrict__ Bw,
    const float* __restrict__ bias, const float2* __restrict__ cst,
    float* __restrict__ outf,
    u16* __restrict__ oq, u16* __restrict__ ok, u16* __restrict__ ov,
    int M, int Nn, int K, int Ntok, int NP) {
  __shared__ u16 A0[4096], B0[4096], A1[4096], B1[4096];
  const int tid = threadIdx.x;
  const int wid = tid >> 6, lane = tid & 63;
  const int wm = wid >> 1, wn = wid & 1;
  const int lg = lane >> 4, lm = lane & 15;
  const int id = blockIdx.x;
  const int chunk = (int)gridDim.x >> 3, nx = Nn >> 7;
  const int swz = (id & 7) * chunk + (id >> 3);  // XCD-bijective (grids % 8 == 0)
  int mtile, ntile;
  if (EPI == 0) {
    // L2-blocked super-tile order (grid 1560 = 65 x 24): 8 stripes of (8M x 24N) walked
    // as 4 sub-panels of (8M x 6N), + ragged m=64 tail.  Bijective.
    if (swz < 1536) {
      int sm = swz / 192, r = swz - sm * 192;
      int sn = r / 48, r2 = r - sn * 48;
      mtile = sm * 8 + (r2 & 7);
      ntile = sn * 6 + (r2 >> 3);
    } else {
      mtile = 64;
      ntile = swz - 1536;
    }
  } else {
    mtile = swz / nx;
    ntile = swz % nx;
  }
  const int mbase = mtile * 128, nbase = ntile * 128;

  const u16* pA0 = stage_src(Aw, mbase, M - 1, K, tid);
  const u16* pA1 = stage_src(Aw, mbase, M - 1, K, 256 + tid);
  const u16* pB0 = stage_src(Bw, nbase, Nn - 1, K, tid);
  const u16* pB1 = stage_src(Bw, nbase, Nn - 1, K, 256 + tid);

  f32x4 acc[4][4];
  const f32x4 zero = {0.f, 0.f, 0.f, 0.f};
#pragma unroll
  for (int a = 0; a < 4; ++a)
#pragma unroll
    for (int b = 0; b < 4; ++b) acc[a][b] = zero;

  stage2(pA0, pA1, A0, 0, tid);
  stage2(pB0, pB1, B0, 0, tid);
  __syncthreads();

  for (int k0 = 0; k0 < K; k0 += 64) {
    if (k0 + 32 < K) {
      stage2(pA0, pA1, A1, k0 + 32, tid);
      stage2(pB0, pB1, B1, k0 + 32, tid);
    }
    {
      f16x8 a[4], w[4];
#pragma unroll
      for (int f = 0; f < 4; ++f) {
        a[f] = *(const f16x8*)&A0[swz_off(wm * 64 + f * 16 + lm, lg)];
        w[f] = *(const f16x8*)&B0[swz_off(wn * 64 + f * 16 + lm, lg)];
      }
#pragma unroll
      for (int fm = 0; fm < 4; ++fm)
#pragma unroll
        for (int fn = 0; fn < 4; ++fn) acc[fm][fn] = MFMAH(a[fm], w[fn], acc[fm][fn]);
    }
    __syncthreads();
    if (k0 + 64 < K) {
      stage2(pA0, pA1, A0, k0 + 64, tid);
      stage2(pB0, pB1, B0, k0 + 64, tid);
    }
    {
      f16x8 a[4], w[4];
#pragma unroll
      for (int f = 0; f < 4; ++f) {
        a[f] = *(const f16x8*)&A1[swz_off(wm * 64 + f * 16 + lm, lg)];
        w[f] = *(const f16x8*)&B1[swz_off(wn * 64 + f * 16 + lm, lg)];
      }
#pragma unroll
      for (int fm = 0; fm < 4; ++fm)
#pragma unroll
        for (int fn = 0; fn < 4; ++fn) acc[fm][fn] = MFMAH(a[fm], w[fn], acc[fm][fn]);
    }
    __syncthreads();
  }

  const int which = (EPI == 0) ? (nbase >> 10) : 1;  // block-uniform q/k/v select
  const bool odd = (lm & 1);
#pragma unroll
  for (int fm = 0; fm < 4; ++fm)
#pragma unroll
    for (int fn = 0; fn < 4; ++fn) {
      int col = nbase + wn * 64 + fn * 16 + lm;
      float bv = bias[col];
      int h2 = (col >> 6) & 15, d2 = col & 63;
#pragma unroll
      for (int i = 0; i < 4; ++i) {
        int row = mbase + wm * 64 + fm * 16 + lg * 4 + i;
        float v = acc[fm][fn][i] + bv;
        float partner = __shfl_xor(v, 1);  // neighbor column (re<->im), uniform exec
        if (row < M) {
          if (EPI == 1) {
            outf[(size_t)row * Nn + col] = v;
          } else {
            int b2 = row / Ntok, t2 = row - b2 * Ntok;
            int bh2 = b2 * 16 + h2;
            if (which == 2) {  // v: f16, written TRANSPOSED [bh][d][NP] (consecutive-t stores)
              ov[(size_t)bh2 * 64 * NP + (size_t)d2 * NP + t2] = f2h(v);
            } else {
              float out = v;
              if (t2 > 0) {
                float2 cs = cst[((size_t)(b2 << 11) + (t2 - 1)) * 32 + (d2 >> 1)];
                out = v * cs.x + (odd ? partner * cs.y : -partner * cs.y);
              }
              if (which == 0) {  // q: fold softmax scale & exp2 conversion
                out *= 0.18033688011112042f;  // 0.125 * log2(e)
                oq[((size_t)bh2 * Ntok + t2) * 64 + d2] = f2h(out);
              } else {  // k: padded row allocation [bh][NP][64]
                ok[((size_t)bh2 * NP + t2) * 64 + d2] = f2h(out);
              }
            }
          }
        }
      }
    }
}

// ---------------- flash attention v8: 4-wave blocks (128 q-rows), lazy cross-lane softmax ----------------
template <bool DO_STAGE, bool TAIL>
__device__ __forceinline__ void attn_tile(
    int kv0, int kvn,
    const u16* Kc, const u16* Vc, u16* Kn, u16* Vn,
    const u16* kgb0, const u16* kgb1, const u16* vgb0, const u16* vgb1,
    int tid, int lg, int lm, int kvbase,
    const f16x8 (&qf16)[2][2],
    float (&m_)[2], float (&l_)[2], f32x4 (&oacc)[2][4],
    unsigned (*pexw)[64][4], int N) {
  if (DO_STAGE) {  // stage NEXT tile (other buffer); 4 insts across 256 threads
    const size_t ko = (size_t)kvn * 64;
    __builtin_amdgcn_global_load_lds(
        (const __attribute__((address_space(1))) void*)(kgb0 + ko),
        (__attribute__((address_space(3))) void*)(Kn + tid * 8), 16, 0, 0);
    __builtin_amdgcn_global_load_lds(
        (const __attribute__((address_space(1))) void*)(kgb1 + ko),
        (__attribute__((address_space(3))) void*)(Kn + 2048 + tid * 8), 16, 0, 0);
    __builtin_amdgcn_global_load_lds(
        (const __attribute__((address_space(1))) void*)(vgb0 + kvn),
        (__attribute__((address_space(3))) void*)(Vn + tid * 8), 16, 0, 0);
    __builtin_amdgcn_global_load_lds(
        (const __attribute__((address_space(1))) void*)(vgb1 + kvn),
        (__attribute__((address_space(3))) void*)(Vn + 2048 + tid * 8), 16, 0, 0);
  }

  const f32x4 zero = {0.f, 0.f, 0.f, 0.f};
  f32x4 s[2][4];
#pragma unroll
  for (int qf = 0; qf < 2; ++qf)
#pragma unroll
    for (int cf = 0; cf < 4; ++cf) s[qf][cf] = zero;
#pragma unroll
  for (int cf = 0; cf < 4; ++cf)
#pragma unroll
    for (int dk = 0; dk < 2; ++dk) {
      f16x8 kf = *(const f16x8*)&Kc[kvbase + dk * 2048 + cf * 128];
      s[0][cf] = MFMAH(kf, qf16[0][dk], s[0][cf]);
      s[1][cf] = MFMAH(kf, qf16[1][dk], s[1][cf]);
    }
  if (TAIL) {
#pragma unroll
    for (int qf = 0; qf < 2; ++qf)
#pragma unroll
      for (int cf = 0; cf < 4; ++cf)
#pragma unroll
        for (int i = 0; i < 4; ++i)
          if (kv0 + cf * 16 + lg * 4 + i >= N) s[qf][cf][i] = -1e30f;
  }

  // softmax (both qf) -> packed f16 words us[qf][8]
  unsigned us[2][8];
#pragma unroll
  for (int qf = 0; qf < 2; ++qf) {
    float t0 = fmaxf(fmaxf(s[qf][0][0], s[qf][0][1]), fmaxf(s[qf][0][2], s[qf][0][3]));
    float t1 = fmaxf(fmaxf(s[qf][1][0], s[qf][1][1]), fmaxf(s[qf][1][2], s[qf][1][3]));
    float t2 = fmaxf(fmaxf(s[qf][2][0], s[qf][2][1]), fmaxf(s[qf][2][2], s[qf][2][3]));
    float t3 = fmaxf(fmaxf(s[qf][3][0], s[qf][3][1]), fmaxf(s[qf][3][2], s[qf][3][3]));
    float mx = fmaxf(fmaxf(t0, t1), fmaxf(t2, t3));
    float mr = m_[qf];
    bool nore = __all(mx - mr <= 8.f) != 0;  // defer-max (lane-local check, equiv to row check)
    float mnew = mr;
    if (!nore) {  // wave-uniform rare branch: full row-max reduce + rescale
      float rmx = fmaxf(mx, __shfl_xor(mx, 16));
      rmx = fmaxf(rmx, __shfl_xor(rmx, 32));
      mnew = fmaxf(mr, rmx);
    }
    float p[16];
#pragma unroll
    for (int cf = 0; cf < 4; ++cf)
#pragma unroll
      for (int i = 0; i < 4; ++i)
        p[cf * 4 + i] = __builtin_amdgcn_exp2f(s[qf][cf][i] - mnew);
    float ps = 0.f;
#pragma unroll
    for (int j = 0; j < 16; ++j) ps += p[j];
    if (nore) {
      l_[qf] += ps;  // per-lane partial; row-reduced in epilogue
    } else {
      float sc = __builtin_amdgcn_exp2f(mr - mnew);
      l_[qf] = l_[qf] * sc + ps;
      m_[qf] = mnew;
#pragma unroll
      for (int c = 0; c < 4; ++c)
#pragma unroll
        for (int i = 0; i < 4; ++i) oacc[qf][c][i] *= sc;
    }
#pragma unroll
    for (int w = 0; w < 8; ++w) us[qf][w] = pkrtz(p[2 * w], p[2 * w + 1]);
  }

  // P exchange: per ks, write both qf regions then read both (DS in-order per wave)
  f16x8 pb[2][2];  // [qf][ks]
  const int ga = (lg & 1) * 2, gb = ga + 1;
  const int cfs2 = (lg >> 1) * 2;
  const int prow = lg * 16 + lm;
#pragma unroll
  for (int ks = 0; ks < 2; ++ks) {
    *(uint4*)&pexw[0][prow][0] =
        make_uint4(us[0][ks * 4], us[0][ks * 4 + 1], us[0][ks * 4 + 2], us[0][ks * 4 + 3]);
    *(uint4*)&pexw[1][prow][0] =
        make_uint4(us[1][ks * 4], us[1][ks * 4 + 1], us[1][ks * 4 + 2], us[1][ks * 4 + 3]);
#pragma unroll
    for (int qf = 0; qf < 2; ++qf) {
      uint2 r0 = *(const uint2*)&pexw[qf][ga * 16 + lm][cfs2];
      uint2 r1 = *(const uint2*)&pexw[qf][gb * 16 + lm][cfs2];
      uint4 pu = make_uint4(r0.x, r0.y, r1.x, r1.y);
      pb[qf][ks] = __builtin_bit_cast(f16x8, pu);
    }
  }

#pragma unroll
  for (int c = 0; c < 4; ++c)
#pragma unroll
    for (int ks = 0; ks < 2; ++ks) {
      f16x8 vh = *(const f16x8*)&Vc[kvbase + ks * 2048 + c * 128];
      oacc[0][c] = MFMAH(vh, pb[0][ks], oacc[0][c]);
      oacc[1][c] = MFMAH(vh, pb[1][ks], oacc[1][c]);
    }
}

__global__ __launch_bounds__(256, 4) void attn_kernel(
    const u16* __restrict__ qh, const u16* __restrict__ kh, const u16* __restrict__ vth,
    u16* __restrict__ outh, int N, int NP) {
  __shared__ u16 K0[4096], V0[4096], K1[4096], V1[4096];
  __shared__ unsigned pexm[4][2][64][4];  // [wave][qf][row][word] — wave-private (8 KB)

  const int id = blockIdx.x;
  const int swz = (id & 7) * 136 + (id >> 3);  // XCD-bijective (1088 = 8*136)
  const int qblk = swz % 17;
  const int bh = swz / 17;
  const int b = bh >> 4, h = bh & 15;
  const int tid = threadIdx.x;
  const int wid = tid >> 6, lane = tid & 63;
  const int lg = lane >> 4, lm = lane & 15;
  const int qbase = qblk * 128 + wid * 32;
  const size_t qoff = (size_t)bh * N * 64;
  const size_t koff = (size_t)bh * NP * 64;
  const size_t voff = (size_t)bh * 64 * NP;

  const int jK = tid & 63, rK = tid >> 6;
  const u16* kgb0 = kh + koff + (size_t)jK * 64 + rK * 8;
  const u16* kgb1 = kgb0 + 32;  // rK+4
  const u16* vgb0 = vth + voff + (size_t)jK * NP + rK * 8;
  const u16* vgb1 = vgb0 + 32;  // kr+4
  const int kvbase = lg * 512 + lm * 8;  // + dk|ks*2048 + cf|c*128

  f16x8 qf16[2][2];
#pragma unroll
  for (int qf = 0; qf < 2; ++qf) {
    int qr = qbase + qf * 16 + lm;
    if (qr > N - 1) qr = N - 1;
    const u16* qp = qh + qoff + (size_t)qr * 64 + lg * 8;
    qf16[qf][0] = *(const f16x8*)(qp);
    qf16[qf][1] = *(const f16x8*)(qp + 32);
  }

  const f32x4 zero = {0.f, 0.f, 0.f, 0.f};
  f32x4 oacc[2][4];
#pragma unroll
  for (int qf = 0; qf < 2; ++qf)
#pragma unroll
    for (int c = 0; c < 4; ++c) oacc[qf][c] = zero;
  float m_[2] = {-1e30f, -1e30f}, l_[2] = {0.f, 0.f};
  unsigned(*pexw)[64][4] = pexm[wid];

  // prologue: stage tile 0 into buffer 0
  __builtin_amdgcn_global_load_lds(
      (const __attribute__((address_space(1))) void*)kgb0,
      (__attribute__((address_space(3))) void*)(K0 + tid * 8), 16, 0, 0);
  __builtin_amdgcn_global_load_lds(
      (const __attribute__((address_space(1))) void*)kgb1,
      (__attribute__((address_space(3))) void*)(K0 + 2048 + tid * 8), 16, 0, 0);
  __builtin_amdgcn_global_load_lds(
      (const __attribute__((address_space(1))) void*)vgb0,
      (__attribute__((address_space(3))) void*)(V0 + tid * 8), 16, 0, 0);
  __builtin_amdgcn_global_load_lds(
      (const __attribute__((address_space(1))) void*)vgb1,
      (__attribute__((address_space(3))) void*)(V0 + 2048 + tid * 8), 16, 0, 0);
  asm volatile("s_waitcnt vmcnt(0)" ::: "memory");
  __builtin_amdgcn_s_barrier();

  for (int t = 0; t < 32; t += 2) {
    attn_tile<true, false>(t * 64, (t + 1) * 64, K0, V0, K1, V1,
                           kgb0, kgb1, vgb0, vgb1,
                           tid, lg, lm, kvbase, qf16, m_, l_, oacc, pexw, N);
    asm volatile("s_waitcnt vmcnt(0)" ::: "memory");
    __builtin_amdgcn_s_barrier();
    attn_tile<true, false>((t + 1) * 64, (t + 2) * 64, K1, V1, K0, V0,
                           kgb0, kgb1, vgb0, vgb1,
                           tid, lg, lm, kvbase, qf16, m_, l_, oacc, pexw, N);
    asm volatile("s_waitcnt vmcnt(0)" ::: "memory");
    __builtin_amdgcn_s_barrier();
  }
  attn_tile<false, true>(32 * 64, 0, K0, V0, K1, V1,
                         kgb0, kgb1, vgb0, vgb1,
                         tid, lg, lm, kvbase, qf16, m_, l_, oacc, pexw, N);

  // epilogue: row-reduce the per-lane l partials, then O/l -> f16 single (RNE)
#pragma unroll
  for (int qf = 0; qf < 2; ++qf) {
    int t = qbase + qf * 16 + lm;
    float lt = l_[qf];
    lt += __shfl_xor(lt, 16);
    lt += __shfl_xor(lt, 32);
    if (t < N) {
      float rl = 1.f / lt;
      size_t rowoff = ((size_t)(b * N + t)) * 1024 + h * 64 + lg * 4;
#pragma unroll
      for (int c = 0; c < 4; ++c) {
        float v0 = oacc[qf][c][0] * rl, v1 = oacc[qf][c][1] * rl;
        float v2 = oacc[qf][c][2] * rl, v3 = oacc[qf][c][3] * rl;
        unsigned hh01 = pk_h(v0, v1), hh23 = pk_h(v2, v3);
        *(uint2*)(outh + rowoff + c * 16) = make_uint2(hh01, hh23);
      }
    }
  }
}

// ---------------- orchestration ----------------
extern "C" void kernel_launch(void* const* d_in, const int* in_sizes, int n_in,
                              void* d_out, int out_size, void* d_ws, size_t ws_size,
                              hipStream_t stream) {
  const float* x     = (const float*)d_in[0];
  const int*   pos   = (const int*)  d_in[1];
  const float* w_qkv = (const float*)d_in[2];
  const float* b_qkv = (const float*)d_in[3];
  const float* w_fc  = (const float*)d_in[4];
  const float* b_fc  = (const float*)d_in[5];
  (void)in_sizes; (void)n_in; (void)out_size; (void)ws_size;

  const int B = 4, N = 2049, NP = 2112;  // NP = 33*64 (KVBLK=64 tiles)
  const long EL = (long)B * N * 1024;       // 8,392,704
  const long ELP = (long)B * 16 * NP * 64;  // padded K elems

  char* base = (char*)d_ws;
  size_t off = 0;
  auto alloc = [&](size_t bytes) -> void* {
    void* p = base + off;
    off += (bytes + 255) & ~(size_t)255;
    return p;
  };
  u16* qhh = (u16*)alloc(EL * 2);                      // q f16 (scaled)
  u16* khh = (u16*)alloc(ELP * 2);                     // k f16 (padded rows)
  u16* vth = (u16*)alloc((size_t)64 * 64 * NP * 2);    // v^T f16 (written directly by gemm<0>)
  u16* xh  = (u16*)alloc(EL * 2);                      // x f16 / attn-out f16
  u16* wq  = (u16*)alloc((size_t)3072 * 1024 * 2);     // w_qkv f16
  u16* wf  = (u16*)alloc((size_t)1024 * 1024 * 2);     // w_fc f16
  float2* cst = (float2*)alloc((size_t)B * 2048 * 32 * 8);

  // 1. fused casts + cos/sin table + pad zeros (pads are disjoint from gemm writes)
  prep_cast<<<2048, 256, 0, stream>>>(x, xh, w_qkv, wq, w_fc, wf,
                                      EL / 4, (long)3072 * 1024 / 4, (long)1024 * 1024 / 4);
  cs_table_kernel<<<(B * 2048 * 32) / 256, 256, 0, stream>>>(pos, cst);
  {
    const int PW = NP - N;
    const int total = 64 * PW * 32 + 64 * 64 * PW;
    pad_kernel<<<(total + 255) / 256, 256, 0, stream>>>(khh, vth, N, NP);
  }
  // 2. fused QKV projection + RoPE + direct-V^T epilogue; grid = 65 x 24 = 1560 (%8==0)
  gemm_s1<0><<<dim3(1560), 256, 0, stream>>>(xh, wq, b_qkv, cst, nullptr,
                                             qhh, khh, vth, 8196, 3072, 1024, N, NP);
  // 3. flash attention (4-wave blocks) -> f16 single into xh; grid 1088 = 8*136
  attn_kernel<<<dim3(1088), 256, 0, stream>>>(qhh, khh, vth, xh, N, NP);
  // 4. output projection (A = attn-out f16) -> d_out; grid = 65 x 8 = 520 (%8==0)
  gemm_s1<1><<<dim3(520), 256, 0, stream>>>(xh, wf, b_fc, nullptr,
                                            (float*)d_out, nullptr, nullptr, nullptr,
                                            8196, 1024, 1024, N, NP);
}

// Round 23
// 307.895 us; speedup vs baseline: 1.0404x; 1.0404x over previous
//
#include <hip/hip_runtime.h>

typedef unsigned short u16;
typedef __attribute__((ext_vector_type(8))) _Float16 f16x8;
typedef __attribute__((ext_vector_type(4))) float f32x4;

#define MFMAH(a, b, c) __builtin_amdgcn_mfma_f32_16x16x32_f16((a), (b), (c), 0, 0, 0)

__device__ __forceinline__ u16 f2h(float f) {
  _Float16 h = (_Float16)f;  // v_cvt_f16_f32, RNE
  return __builtin_bit_cast(u16, h);
}
__device__ __forceinline__ float h2f(u16 h) {
  return (float)__builtin_bit_cast(_Float16, h);
}
__device__ __forceinline__ unsigned pk_h(float a, float b) {  // RNE pair
  return (unsigned)f2h(a) | ((unsigned)f2h(b) << 16);
}
__device__ __forceinline__ unsigned pkrtz(float a, float b) {  // 1-inst packed cvt (RTZ)
  unsigned r;
  asm("v_cvt_pkrtz_f16_f32 %0, %1, %2" : "=v"(r) : "v"(a), "v"(b));
  return r;
}

// ---------------- fused prep: cast x, w_qkv, w_fc to f16 (one launch) ----------------
__global__ void prep_cast(const float* __restrict__ x, u16* __restrict__ xh,
                          const float* __restrict__ wqf, u16* __restrict__ wq,
                          const float* __restrict__ wff, u16* __restrict__ wf,
                          long nx, long nq, long nf) {
  long total = nx + nq + nf;
  long stride = (long)gridDim.x * blockDim.x;
  for (long i = (long)blockIdx.x * blockDim.x + threadIdx.x; i < total; i += stride) {
    const float4* src;
    ushort4* dst;
    long j;
    if (i < nx) { src = (const float4*)x; dst = (ushort4*)xh; j = i; }
    else if (i < nx + nq) { src = (const float4*)wqf; dst = (ushort4*)wq; j = i - nx; }
    else { src = (const float4*)wff; dst = (ushort4*)wf; j = i - nx - nq; }
    float4 v = src[j];
    ushort4 h;
    h.x = f2h(v.x); h.y = f2h(v.y); h.z = f2h(v.z); h.w = f2h(v.w);
    dst[j] = h;
  }
}

// ---------------- cos/sin table: (b, t-1, i) -> float2(c,s); 16 heads share positions ----------------
__global__ void cs_table_kernel(const int* __restrict__ pos, float2* __restrict__ cst) {
  int idx = blockIdx.x * 256 + threadIdx.x;  // exactly B*2048*32 threads
  int i = idx & 31;
  int r = idx >> 5;
  int ti = r & 2047;
  int b = r >> 11;
  int p = pos[b * 2048 + ti];
  // replicate reference fp32 rounding of freq and angle, then exact trig
  float fr = (float)pow(10000.0, -(double)i / 32.0);
  float angf = (float)p * fr;
  double sd, cd;
  sincos((double)angf, &sd, &cd);
  cst[idx] = make_float2((float)cd, (float)sd);
}

// ---------------- pads: zero K rows [N,NP) and V^T cols [N,NP) (f16) ----------------
__global__ void pad_kernel(u16* __restrict__ kh, u16* __restrict__ vth, int N, int NP) {
  const int PW = NP - N;                 // 63 pad tokens
  const int PART1 = 64 * PW * 32;        // u32 words for K pad rows
  const int PART2 = 64 * 64 * PW;        // u16 elems for V^T pad cols
  int idx = blockIdx.x * 256 + threadIdx.x;
  if (idx < PART1) {
    int per_bh = PW * 32;
    int bh = idx / per_bh, r = idx - bh * per_bh;
    size_t u = (((size_t)bh * NP + N) * 64 >> 1) + r;
    ((unsigned*)kh)[u] = 0;
  } else if (idx < PART1 + PART2) {
    int j = idx - PART1;
    int per_bh = 64 * PW;
    int bh = j / per_bh, r = j - bh * per_bh;
    int d = r / PW, t = N + (r - d * PW);
    vth[(size_t)bh * 64 * NP + (size_t)d * NP + t] = 0;
  }
}

// ================= f16 GEMM (R21 champion: 2-phase, 5 blocks/CU, hoisted ptrs) =================
// BM=128 x BN=128 x BK=32, 256 thr = 4 waves, wave-tile 64x64, 2-phase dbuf, 32 KB LDS.
// Ledger: counted-vmcnt x3 regressed; L2-blocked traversal (R22) cut FETCH 154->68 MB but
// regressed dur (L2 hot-spot serialization) -> simple XCD-chunk order is the winner.
__device__ __forceinline__ int swz_off(int R, int lg) {
  return R * 32 + ((lg ^ ((R >> 1) & 3)) << 3);
}
__device__ __forceinline__ const u16* stage_src(const u16* __restrict__ g, int row0, int rmax,
                                                int K, int c) {
  int row = c >> 2;
  int kc = (((c & 3) ^ ((c >> 3) & 3)) << 3);
  int gr = row0 + row;
  if (gr > rmax) gr = rmax;
  return g + (size_t)gr * K + kc;
}
__device__ __forceinline__ void stage2(const u16* p0, const u16* p1, u16* l, int k0, int tid) {
  __builtin_amdgcn_global_load_lds((const __attribute__((address_space(1))) void*)(p0 + k0),
                                   (__attribute__((address_space(3))) void*)(l + tid * 8),
                                   16, 0, 0);
  __builtin_amdgcn_global_load_lds((const __attribute__((address_space(1))) void*)(p1 + k0),
                                   (__attribute__((address_space(3))) void*)(l + 2048 + tid * 8),
                                   16, 0, 0);
}

// EPI 0: fused RoPE + f16 q/k epilogue + direct-transposed v.  EPI 1: fp32 out + bias.
template <int EPI>
__global__ __launch_bounds__(256) void gemm_s1(
    const u16* __restrict__ Aw, const u16* __restrict__ Bw,
    const float* __restrict__ bias, const float2* __restrict__ cst,
    float* __restrict__ outf,
    u16* __restrict__ oq, u16* __restrict__ ok, u16* __restrict__ ov,
    int M, int Nn, int K, int Ntok, int NP) {
  __shared__ u16 A0[4096], B0[4096], A1[4096], B1[4096];
  const int tid = threadIdx.x;
  const int wid = tid >> 6, lane = tid & 63;
  const int wm = wid >> 1, wn = wid & 1;
  const int lg = lane >> 4, lm = lane & 15;
  const int id = blockIdx.x;
  const int chunk = (int)gridDim.x >> 3, nx = Nn >> 7;
  const int swz = (id & 7) * chunk + (id >> 3);  // XCD-bijective (grids % 8 == 0)
  const int mbase = (swz / nx) * 128, nbase = (swz % nx) * 128;

  const u16* pA0 = stage_src(Aw, mbase, M - 1, K, tid);
  const u16* pA1 = stage_src(Aw, mbase, M - 1, K, 256 + tid);
  const u16* pB0 = stage_src(Bw, nbase, Nn - 1, K, tid);
  const u16* pB1 = stage_src(Bw, nbase, Nn - 1, K, 256 + tid);

  f32x4 acc[4][4];
  const f32x4 zero = {0.f, 0.f, 0.f, 0.f};
#pragma unroll
  for (int a = 0; a < 4; ++a)
#pragma unroll
    for (int b = 0; b < 4; ++b) acc[a][b] = zero;

  stage2(pA0, pA1, A0, 0, tid);
  stage2(pB0, pB1, B0, 0, tid);
  __syncthreads();

  for (int k0 = 0; k0 < K; k0 += 64) {
    if (k0 + 32 < K) {
      stage2(pA0, pA1, A1, k0 + 32, tid);
      stage2(pB0, pB1, B1, k0 + 32, tid);
    }
    {
      f16x8 a[4], w[4];
#pragma unroll
      for (int f = 0; f < 4; ++f) {
        a[f] = *(const f16x8*)&A0[swz_off(wm * 64 + f * 16 + lm, lg)];
        w[f] = *(const f16x8*)&B0[swz_off(wn * 64 + f * 16 + lm, lg)];
      }
#pragma unroll
      for (int fm = 0; fm < 4; ++fm)
#pragma unroll
        for (int fn = 0; fn < 4; ++fn) acc[fm][fn] = MFMAH(a[fm], w[fn], acc[fm][fn]);
    }
    __syncthreads();
    if (k0 + 64 < K) {
      stage2(pA0, pA1, A0, k0 + 64, tid);
      stage2(pB0, pB1, B0, k0 + 64, tid);
    }
    {
      f16x8 a[4], w[4];
#pragma unroll
      for (int f = 0; f < 4; ++f) {
        a[f] = *(const f16x8*)&A1[swz_off(wm * 64 + f * 16 + lm, lg)];
        w[f] = *(const f16x8*)&B1[swz_off(wn * 64 + f * 16 + lm, lg)];
      }
#pragma unroll
      for (int fm = 0; fm < 4; ++fm)
#pragma unroll
        for (int fn = 0; fn < 4; ++fn) acc[fm][fn] = MFMAH(a[fm], w[fn], acc[fm][fn]);
    }
    __syncthreads();
  }

  const int which = (EPI == 0) ? (nbase >> 10) : 1;  // block-uniform q/k/v select
  const bool odd = (lm & 1);
#pragma unroll
  for (int fm = 0; fm < 4; ++fm)
#pragma unroll
    for (int fn = 0; fn < 4; ++fn) {
      int col = nbase + wn * 64 + fn * 16 + lm;
      float bv = bias[col];
      int h2 = (col >> 6) & 15, d2 = col & 63;
#pragma unroll
      for (int i = 0; i < 4; ++i) {
        int row = mbase + wm * 64 + fm * 16 + lg * 4 + i;
        float v = acc[fm][fn][i] + bv;
        float partner = __shfl_xor(v, 1);  // neighbor column (re<->im), uniform exec
        if (row < M) {
          if (EPI == 1) {
            outf[(size_t)row * Nn + col] = v;
          } else {
            int b2 = row / Ntok, t2 = row - b2 * Ntok;
            int bh2 = b2 * 16 + h2;
            if (which == 2) {  // v: f16, written TRANSPOSED [bh][d][NP] (consecutive-t stores)
              ov[(size_t)bh2 * 64 * NP + (size_t)d2 * NP + t2] = f2h(v);
            } else {
              float out = v;
              if (t2 > 0) {
                float2 cs = cst[((size_t)(b2 << 11) + (t2 - 1)) * 32 + (d2 >> 1)];
                out = v * cs.x + (odd ? partner * cs.y : -partner * cs.y);
              }
              if (which == 0) {  // q: fold softmax scale & exp2 conversion
                out *= 0.18033688011112042f;  // 0.125 * log2(e)
                oq[((size_t)bh2 * Ntok + t2) * 64 + d2] = f2h(out);
              } else {  // k: padded row allocation [bh][NP][64]
                ok[((size_t)bh2 * NP + t2) * 64 + d2] = f2h(out);
              }
            }
          }
        }
      }
    }
}

// ---------------- flash attention v8: 4-wave blocks (128 q-rows), lazy cross-lane softmax ----------------
template <bool DO_STAGE, bool TAIL>
__device__ __forceinline__ void attn_tile(
    int kv0, int kvn,
    const u16* Kc, const u16* Vc, u16* Kn, u16* Vn,
    const u16* kgb0, const u16* kgb1, const u16* vgb0, const u16* vgb1,
    int tid, int lg, int lm, int kvbase,
    const f16x8 (&qf16)[2][2],
    float (&m_)[2], float (&l_)[2], f32x4 (&oacc)[2][4],
    unsigned (*pexw)[64][4], int N) {
  if (DO_STAGE) {  // stage NEXT tile (other buffer); 4 insts across 256 threads
    const size_t ko = (size_t)kvn * 64;
    __builtin_amdgcn_global_load_lds(
        (const __attribute__((address_space(1))) void*)(kgb0 + ko),
        (__attribute__((address_space(3))) void*)(Kn + tid * 8), 16, 0, 0);
    __builtin_amdgcn_global_load_lds(
        (const __attribute__((address_space(1))) void*)(kgb1 + ko),
        (__attribute__((address_space(3))) void*)(Kn + 2048 + tid * 8), 16, 0, 0);
    __builtin_amdgcn_global_load_lds(
        (const __attribute__((address_space(1))) void*)(vgb0 + kvn),
        (__attribute__((address_space(3))) void*)(Vn + tid * 8), 16, 0, 0);
    __builtin_amdgcn_global_load_lds(
        (const __attribute__((address_space(1))) void*)(vgb1 + kvn),
        (__attribute__((address_space(3))) void*)(Vn + 2048 + tid * 8), 16, 0, 0);
  }

  const f32x4 zero = {0.f, 0.f, 0.f, 0.f};
  f32x4 s[2][4];
#pragma unroll
  for (int qf = 0; qf < 2; ++qf)
#pragma unroll
    for (int cf = 0; cf < 4; ++cf) s[qf][cf] = zero;
#pragma unroll
  for (int cf = 0; cf < 4; ++cf)
#pragma unroll
    for (int dk = 0; dk < 2; ++dk) {
      f16x8 kf = *(const f16x8*)&Kc[kvbase + dk * 2048 + cf * 128];
      s[0][cf] = MFMAH(kf, qf16[0][dk], s[0][cf]);
      s[1][cf] = MFMAH(kf, qf16[1][dk], s[1][cf]);
    }
  if (TAIL) {
#pragma unroll
    for (int qf = 0; qf < 2; ++qf)
#pragma unroll
      for (int cf = 0; cf < 4; ++cf)
#pragma unroll
        for (int i = 0; i < 4; ++i)
          if (kv0 + cf * 16 + lg * 4 + i >= N) s[qf][cf][i] = -1e30f;
  }

  // softmax (both qf) -> packed f16 words us[qf][8]
  unsigned us[2][8];
#pragma unroll
  for (int qf = 0; qf < 2; ++qf) {
    float t0 = fmaxf(fmaxf(s[qf][0][0], s[qf][0][1]), fmaxf(s[qf][0][2], s[qf][0][3]));
    float t1 = fmaxf(fmaxf(s[qf][1][0], s[qf][1][1]), fmaxf(s[qf][1][2], s[qf][1][3]));
    float t2 = fmaxf(fmaxf(s[qf][2][0], s[qf][2][1]), fmaxf(s[qf][2][2], s[qf][2][3]));
    float t3 = fmaxf(fmaxf(s[qf][3][0], s[qf][3][1]), fmaxf(s[qf][3][2], s[qf][3][3]));
    float mx = fmaxf(fmaxf(t0, t1), fmaxf(t2, t3));
    float mr = m_[qf];
    bool nore = __all(mx - mr <= 8.f) != 0;  // defer-max (lane-local check, equiv to row check)
    float mnew = mr;
    if (!nore) {  // wave-uniform rare branch: full row-max reduce + rescale
      float rmx = fmaxf(mx, __shfl_xor(mx, 16));
      rmx = fmaxf(rmx, __shfl_xor(rmx, 32));
      mnew = fmaxf(mr, rmx);
    }
    float p[16];
#pragma unroll
    for (int cf = 0; cf < 4; ++cf)
#pragma unroll
      for (int i = 0; i < 4; ++i)
        p[cf * 4 + i] = __builtin_amdgcn_exp2f(s[qf][cf][i] - mnew);
    float ps = 0.f;
#pragma unroll
    for (int j = 0; j < 16; ++j) ps += p[j];
    if (nore) {
      l_[qf] += ps;  // per-lane partial; row-reduced in epilogue
    } else {
      float sc = __builtin_amdgcn_exp2f(mr - mnew);
      l_[qf] = l_[qf] * sc + ps;
      m_[qf] = mnew;
#pragma unroll
      for (int c = 0; c < 4; ++c)
#pragma unroll
        for (int i = 0; i < 4; ++i) oacc[qf][c][i] *= sc;
    }
#pragma unroll
    for (int w = 0; w < 8; ++w) us[qf][w] = pkrtz(p[2 * w], p[2 * w + 1]);
  }

  // P exchange: per ks, write both qf regions then read both (DS in-order per wave)
  f16x8 pb[2][2];  // [qf][ks]
  const int ga = (lg & 1) * 2, gb = ga + 1;
  const int cfs2 = (lg >> 1) * 2;
  const int prow = lg * 16 + lm;
#pragma unroll
  for (int ks = 0; ks < 2; ++ks) {
    *(uint4*)&pexw[0][prow][0] =
        make_uint4(us[0][ks * 4], us[0][ks * 4 + 1], us[0][ks * 4 + 2], us[0][ks * 4 + 3]);
    *(uint4*)&pexw[1][prow][0] =
        make_uint4(us[1][ks * 4], us[1][ks * 4 + 1], us[1][ks * 4 + 2], us[1][ks * 4 + 3]);
#pragma unroll
    for (int qf = 0; qf < 2; ++qf) {
      uint2 r0 = *(const uint2*)&pexw[qf][ga * 16 + lm][cfs2];
      uint2 r1 = *(const uint2*)&pexw[qf][gb * 16 + lm][cfs2];
      uint4 pu = make_uint4(r0.x, r0.y, r1.x, r1.y);
      pb[qf][ks] = __builtin_bit_cast(f16x8, pu);
    }
  }

#pragma unroll
  for (int c = 0; c < 4; ++c)
#pragma unroll
    for (int ks = 0; ks < 2; ++ks) {
      f16x8 vh = *(const f16x8*)&Vc[kvbase + ks * 2048 + c * 128];
      oacc[0][c] = MFMAH(vh, pb[0][ks], oacc[0][c]);
      oacc[1][c] = MFMAH(vh, pb[1][ks], oacc[1][c]);
    }
}

__global__ __launch_bounds__(256, 4) void attn_kernel(
    const u16* __restrict__ qh, const u16* __restrict__ kh, const u16* __restrict__ vth,
    u16* __restrict__ outh, int N, int NP) {
  __shared__ u16 K0[4096], V0[4096], K1[4096], V1[4096];
  __shared__ unsigned pexm[4][2][64][4];  // [wave][qf][row][word] — wave-private (8 KB)

  const int id = blockIdx.x;
  const int swz = (id & 7) * 136 + (id >> 3);  // XCD-bijective (1088 = 8*136)
  const int qblk = swz % 17;
  const int bh = swz / 17;
  const int b = bh >> 4, h = bh & 15;
  const int tid = threadIdx.x;
  const int wid = tid >> 6, lane = tid & 63;
  const int lg = lane >> 4, lm = lane & 15;
  const int qbase = qblk * 128 + wid * 32;
  const size_t qoff = (size_t)bh * N * 64;
  const size_t koff = (size_t)bh * NP * 64;
  const size_t voff = (size_t)bh * 64 * NP;

  const int jK = tid & 63, rK = tid >> 6;
  const u16* kgb0 = kh + koff + (size_t)jK * 64 + rK * 8;
  const u16* kgb1 = kgb0 + 32;  // rK+4
  const u16* vgb0 = vth + voff + (size_t)jK * NP + rK * 8;
  const u16* vgb1 = vgb0 + 32;  // kr+4
  const int kvbase = lg * 512 + lm * 8;  // + dk|ks*2048 + cf|c*128

  f16x8 qf16[2][2];
#pragma unroll
  for (int qf = 0; qf < 2; ++qf) {
    int qr = qbase + qf * 16 + lm;
    if (qr > N - 1) qr = N - 1;
    const u16* qp = qh + qoff + (size_t)qr * 64 + lg * 8;
    qf16[qf][0] = *(const f16x8*)(qp);
    qf16[qf][1] = *(const f16x8*)(qp + 32);
  }

  const f32x4 zero = {0.f, 0.f, 0.f, 0.f};
  f32x4 oacc[2][4];
#pragma unroll
  for (int qf = 0; qf < 2; ++qf)
#pragma unroll
    for (int c = 0; c < 4; ++c) oacc[qf][c] = zero;
  float m_[2] = {-1e30f, -1e30f}, l_[2] = {0.f, 0.f};
  unsigned(*pexw)[64][4] = pexm[wid];

  // prologue: stage tile 0 into buffer 0
  __builtin_amdgcn_global_load_lds(
      (const __attribute__((address_space(1))) void*)kgb0,
      (__attribute__((address_space(3))) void*)(K0 + tid * 8), 16, 0, 0);
  __builtin_amdgcn_global_load_lds(
      (const __attribute__((address_space(1))) void*)kgb1,
      (__attribute__((address_space(3))) void*)(K0 + 2048 + tid * 8), 16, 0, 0);
  __builtin_amdgcn_global_load_lds(
      (const __attribute__((address_space(1))) void*)vgb0,
      (__attribute__((address_space(3))) void*)(V0 + tid * 8), 16, 0, 0);
  __builtin_amdgcn_global_load_lds(
      (const __attribute__((address_space(1))) void*)vgb1,
      (__attribute__((address_space(3))) void*)(V0 + 2048 + tid * 8), 16, 0, 0);
  asm volatile("s_waitcnt vmcnt(0)" ::: "memory");
  __builtin_amdgcn_s_barrier();

  for (int t = 0; t < 32; t += 2) {
    attn_tile<true, false>(t * 64, (t + 1) * 64, K0, V0, K1, V1,
                           kgb0, kgb1, vgb0, vgb1,
                           tid, lg, lm, kvbase, qf16, m_, l_, oacc, pexw, N);
    asm volatile("s_waitcnt vmcnt(0)" ::: "memory");
    __builtin_amdgcn_s_barrier();
    attn_tile<true, false>((t + 1) * 64, (t + 2) * 64, K1, V1, K0, V0,
                           kgb0, kgb1, vgb0, vgb1,
                           tid, lg, lm, kvbase, qf16, m_, l_, oacc, pexw, N);
    asm volatile("s_waitcnt vmcnt(0)" ::: "memory");
    __builtin_amdgcn_s_barrier();
  }
  attn_tile<false, true>(32 * 64, 0, K0, V0, K1, V1,
                         kgb0, kgb1, vgb0, vgb1,
                         tid, lg, lm, kvbase, qf16, m_, l_, oacc, pexw, N);

  // epilogue: row-reduce the per-lane l partials, then O/l -> f16 single (RNE)
#pragma unroll
  for (int qf = 0; qf < 2; ++qf) {
    int t = qbase + qf * 16 + lm;
    float lt = l_[qf];
    lt += __shfl_xor(lt, 16);
    lt += __shfl_xor(lt, 32);
    if (t < N) {
      float rl = 1.f / lt;
      size_t rowoff = ((size_t)(b * N + t)) * 1024 + h * 64 + lg * 4;
#pragma unroll
      for (int c = 0; c < 4; ++c) {
        float v0 = oacc[qf][c][0] * rl, v1 = oacc[qf][c][1] * rl;
        float v2 = oacc[qf][c][2] * rl, v3 = oacc[qf][c][3] * rl;
        unsigned hh01 = pk_h(v0, v1), hh23 = pk_h(v2, v3);
        *(uint2*)(outh + rowoff + c * 16) = make_uint2(hh01, hh23);
      }
    }
  }
}

// ---------------- orchestration ----------------
extern "C" void kernel_launch(void* const* d_in, const int* in_sizes, int n_in,
                              void* d_out, int out_size, void* d_ws, size_t ws_size,
                              hipStream_t stream) {
  const float* x     = (const float*)d_in[0];
  const int*   pos   = (const int*)  d_in[1];
  const float* w_qkv = (const float*)d_in[2];
  const float* b_qkv = (const float*)d_in[3];
  const float* w_fc  = (const float*)d_in[4];
  const float* b_fc  = (const float*)d_in[5];
  (void)in_sizes; (void)n_in; (void)out_size; (void)ws_size;

  const int B = 4, N = 2049, NP = 2112;  // NP = 33*64 (KVBLK=64 tiles)
  const long EL = (long)B * N * 1024;       // 8,392,704
  const long ELP = (long)B * 16 * NP * 64;  // padded K elems

  char* base = (char*)d_ws;
  size_t off = 0;
  auto alloc = [&](size_t bytes) -> void* {
    void* p = base + off;
    off += (bytes + 255) & ~(size_t)255;
    return p;
  };
  u16* qhh = (u16*)alloc(EL * 2);                      // q f16 (scaled)
  u16* khh = (u16*)alloc(ELP * 2);                     // k f16 (padded rows)
  u16* vth = (u16*)alloc((size_t)64 * 64 * NP * 2);    // v^T f16 (written directly by gemm<0>)
  u16* xh  = (u16*)alloc(EL * 2);                      // x f16 / attn-out f16
  u16* wq  = (u16*)alloc((size_t)3072 * 1024 * 2);     // w_qkv f16
  u16* wf  = (u16*)alloc((size_t)1024 * 1024 * 2);     // w_fc f16
  float2* cst = (float2*)alloc((size_t)B * 2048 * 32 * 8);

  // 1. fused casts + cos/sin table + pad zeros (pads are disjoint from gemm writes)
  prep_cast<<<2048, 256, 0, stream>>>(x, xh, w_qkv, wq, w_fc, wf,
                                      EL / 4, (long)3072 * 1024 / 4, (long)1024 * 1024 / 4);
  cs_table_kernel<<<(B * 2048 * 32) / 256, 256, 0, stream>>>(pos, cst);
  {
    const int PW = NP - N;
    const int total = 64 * PW * 32 + 64 * 64 * PW;
    pad_kernel<<<(total + 255) / 256, 256, 0, stream>>>(khh, vth, N, NP);
  }
  // 2. fused QKV projection + RoPE + direct-V^T epilogue; grid = 65 x 24 = 1560 (%8==0)
  gemm_s1<0><<<dim3(1560), 256, 0, stream>>>(xh, wq, b_qkv, cst, nullptr,
                                             qhh, khh, vth, 8196, 3072, 1024, N, NP);
  // 3. flash attention (4-wave blocks) -> f16 single into xh; grid 1088 = 8*136
  attn_kernel<<<dim3(1088), 256, 0, stream>>>(qhh, khh, vth, xh, N, NP);
  // 4. output projection (A = attn-out f16) -> d_out; grid = 65 x 8 = 520 (%8==0)
  gemm_s1<1><<<dim3(520), 256, 0, stream>>>(xh, wf, b_fc, nullptr,
                                            (float*)d_out, nullptr, nullptr, nullptr,
                                            8196, 1024, 1024, N, NP);
}